// Round 6
// baseline (4266.184 us; speedup 1.0000x reference)
//
#include <hip/hip_runtime.h>
#include <hip/hip_bf16.h>
#include <math.h>

typedef __hip_bfloat16 bf16;
typedef __attribute__((ext_vector_type(2))) float f32x2;

// Problem constants (fixed by reference)
#define B_      8
#define S_      2048
#define DIN     1024
#define DSTATE  1024
#define H_      16
#define DH_     64
#define PROJ4   4096   // 4*DSTATE

// ---------------------------------------------------------------------------
// bf16 <-> f32 helpers (bit-level, RNE for store)
// ---------------------------------------------------------------------------
__device__ __forceinline__ unsigned short f2bf(float f) {
    unsigned int x = __float_as_uint(f);
    x += 0x7FFFu + ((x >> 16) & 1u);   // round-to-nearest-even
    return (unsigned short)(x >> 16);
}

__device__ __forceinline__ float4 load4(const float* p) { return *(const float4*)p; }
__device__ __forceinline__ float4 load4(const bf16* p) {
    uint2 u = *(const uint2*)p;    // 4 bf16 = 8 bytes
    float4 r;
    r.x = __uint_as_float((u.x & 0xFFFFu) << 16);
    r.y = __uint_as_float(u.x & 0xFFFF0000u);
    r.z = __uint_as_float((u.y & 0xFFFFu) << 16);
    r.w = __uint_as_float(u.y & 0xFFFF0000u);
    return r;
}
__device__ __forceinline__ void store4(float* p, float4 v) { *(float4*)p = v; }
__device__ __forceinline__ void store4(bf16* p, float4 v) {
    uint2 u;
    u.x = (unsigned int)f2bf(v.x) | ((unsigned int)f2bf(v.y) << 16);
    u.y = (unsigned int)f2bf(v.z) | ((unsigned int)f2bf(v.w) << 16);
    *(uint2*)p = u;
}

// ---------------------------------------------------------------------------
// MFMA bf16 GEMM (unchanged from R4/R5 — recur is this round's target).
// ---------------------------------------------------------------------------
typedef __attribute__((ext_vector_type(8))) short bf16x8;
typedef __attribute__((ext_vector_type(4))) float f32x4;
typedef __attribute__((ext_vector_type(4))) short short4v;

template <typename TA>
__device__ __forceinline__ void load_a4(const TA* p, float out[4]);
template <>
__device__ __forceinline__ void load_a4<float>(const float* p, float out[4]) {
    float4 v = *(const float4*)p;
    out[0] = v.x; out[1] = v.y; out[2] = v.z; out[3] = v.w;
}
template <>
__device__ __forceinline__ void load_a4<bf16>(const bf16* p, float out[4]) {
    float4 v = load4(p);
    out[0] = v.x; out[1] = v.y; out[2] = v.z; out[3] = v.w;
}

template <typename TA, typename TC>
__global__ __launch_bounds__(256) void gemm_mfma(const TA* __restrict__ A,
                                                 const float* __restrict__ Bm,
                                                 TC* __restrict__ C,
                                                 int M, int N, int K, int lda) {
    __shared__ short As[128][40];   // As[m][k], k contiguous
    __shared__ short Bs[128][40];   // Bs[n][k], k contiguous (B transposed)

    const int tid = threadIdx.x;
    const int m0 = blockIdx.y * 128;
    const int n0 = blockIdx.x * 128;

    const int saM = tid >> 1;              // 0..127
    const int saK = (tid & 1) * 16;        // 0 or 16
    const int sbK = tid >> 3;              // 0..31
    const int sbN = (tid & 7) * 16;        // 0..112

    const int wid = tid >> 6;
    const int wx = wid & 1, wy = wid >> 1; // 2x2 wave grid
    const int lane = tid & 63;
    const int c16 = lane & 15;
    const int quad = lane >> 4;

    const TA* Aptr = A + (size_t)(m0 + saM) * lda + saK;
    const float* Bptr = Bm + (size_t)sbK * N + n0 + sbN;

    f32x4 acc[4][4];
    #pragma unroll
    for (int i = 0; i < 4; ++i)
        #pragma unroll
        for (int j = 0; j < 4; ++j) acc[i][j] = (f32x4){0.f, 0.f, 0.f, 0.f};

    float ra[4][4];
    float rb[4][4];
    #pragma unroll
    for (int i = 0; i < 4; ++i) load_a4<TA>(Aptr + i * 4, ra[i]);
    #pragma unroll
    for (int i = 0; i < 4; ++i) {
        float4 v = load4(Bptr + i * 4);
        rb[i][0] = v.x; rb[i][1] = v.y; rb[i][2] = v.z; rb[i][3] = v.w;
    }

    for (int k0 = 0; k0 < K; k0 += 32) {
        __syncthreads();
        #pragma unroll
        for (int i = 0; i < 4; ++i) {
            short4v pk = { (short)f2bf(ra[i][0]), (short)f2bf(ra[i][1]),
                           (short)f2bf(ra[i][2]), (short)f2bf(ra[i][3]) };
            *(short4v*)&As[saM][saK + i * 4] = pk;
        }
        #pragma unroll
        for (int i = 0; i < 4; ++i)
            #pragma unroll
            for (int j = 0; j < 4; ++j)
                Bs[sbN + i * 4 + j][sbK] = (short)f2bf(rb[i][j]);
        __syncthreads();

        if (k0 + 32 < K) {
            #pragma unroll
            for (int i = 0; i < 4; ++i) load_a4<TA>(Aptr + k0 + 32 + i * 4, ra[i]);
            #pragma unroll
            for (int i = 0; i < 4; ++i) {
                float4 v = load4(Bptr + (size_t)(k0 + 32) * N + i * 4);
                rb[i][0] = v.x; rb[i][1] = v.y; rb[i][2] = v.z; rb[i][3] = v.w;
            }
        }

        bf16x8 af[4], bfr[4];
        #pragma unroll
        for (int mt = 0; mt < 4; ++mt)
            af[mt] = *(const bf16x8*)&As[wy * 64 + mt * 16 + c16][quad * 8];
        #pragma unroll
        for (int nt = 0; nt < 4; ++nt)
            bfr[nt] = *(const bf16x8*)&Bs[wx * 64 + nt * 16 + c16][quad * 8];

        #pragma unroll
        for (int mt = 0; mt < 4; ++mt)
            #pragma unroll
            for (int nt = 0; nt < 4; ++nt)
                acc[mt][nt] = __builtin_amdgcn_mfma_f32_16x16x32_bf16(
                    af[mt], bfr[nt], acc[mt][nt], 0, 0, 0);
    }

    #pragma unroll
    for (int mt = 0; mt < 4; ++mt) {
        #pragma unroll
        for (int r = 0; r < 4; ++r) {
            int row = m0 + wy * 64 + mt * 16 + quad * 4 + r;
            TC* cp = C + (size_t)row * N + n0 + wx * 64;
            #pragma unroll
            for (int nt = 0; nt < 4; ++nt)
                cp[nt * 16 + c16] = (TC)acc[mt][nt][r];
        }
    }
}

// ---------------------------------------------------------------------------
// Recurrence: ONE wave per (b,h) chain; no barriers, no readlane, no LDS
// storage. Lane e owns h[e]. h[d] broadcasts use ds_swizzle (BitMode or-mask
// = lane-broadcast within each 32-lane half); two full-wave replicas
// h_lo[j]=h[j], h_hi[j]=h[32+j] (maintained with 2 full-wave ds_bpermute per
// step) make the half-scoped swizzle reach all 64 lanes. Matvec FMAs run as
// v_pk_fma_f32 on pre-paired weights (halves VALU issue).
// ---------------------------------------------------------------------------
template<int DP>
struct RFLoop {
    static __device__ __forceinline__ void run(int hlo, int hhi,
            const f32x2 (&Wr)[32], const f32x2 (&Wf)[32],
            f32x2& ar0, f32x2& ar1, f32x2& af0, f32x2& af1) {
        constexpr int base = (DP < 16) ? (2 * DP) : (2 * DP - 32);
        int hs = (DP < 16) ? hlo : hhi;
        f32x2 hp;
        hp.x = __int_as_float(__builtin_amdgcn_ds_swizzle(hs, (base) << 5));
        hp.y = __int_as_float(__builtin_amdgcn_ds_swizzle(hs, (base + 1) << 5));
        if constexpr (DP & 1) {
            asm("v_pk_fma_f32 %0, %1, %2, %0" : "+v"(ar1) : "v"(Wr[DP]), "v"(hp));
            asm("v_pk_fma_f32 %0, %1, %2, %0" : "+v"(af1) : "v"(Wf[DP]), "v"(hp));
        } else {
            asm("v_pk_fma_f32 %0, %1, %2, %0" : "+v"(ar0) : "v"(Wr[DP]), "v"(hp));
            asm("v_pk_fma_f32 %0, %1, %2, %0" : "+v"(af0) : "v"(Wf[DP]), "v"(hp));
        }
        RFLoop<DP + 1>::run(hlo, hhi, Wr, Wf, ar0, ar1, af0, af1);
    }
};
template<>
struct RFLoop<32> {
    static __device__ __forceinline__ void run(int, int, const f32x2 (&)[32],
            const f32x2 (&)[32], f32x2&, f32x2&, f32x2&, f32x2&) {}
};

template<int DP>
struct CLoop {
    static __device__ __forceinline__ void run(int rlo, int rhi,
            const f32x2 (&Wc)[32], f32x2& ac0, f32x2& ac1) {
        constexpr int base = (DP < 16) ? (2 * DP) : (2 * DP - 32);
        int hs = (DP < 16) ? rlo : rhi;
        f32x2 hp;
        hp.x = __int_as_float(__builtin_amdgcn_ds_swizzle(hs, (base) << 5));
        hp.y = __int_as_float(__builtin_amdgcn_ds_swizzle(hs, (base + 1) << 5));
        if constexpr (DP & 1) {
            asm("v_pk_fma_f32 %0, %1, %2, %0" : "+v"(ac1) : "v"(Wc[DP]), "v"(hp));
        } else {
            asm("v_pk_fma_f32 %0, %1, %2, %0" : "+v"(ac0) : "v"(Wc[DP]), "v"(hp));
        }
        CLoop<DP + 1>::run(rlo, rhi, Wc, ac0, ac1);
    }
};
template<>
struct CLoop<32> {
    static __device__ __forceinline__ void run(int, int, const f32x2 (&)[32],
            f32x2&, f32x2&) {}
};

__global__ __launch_bounds__(64, 1) void recur_kernel(bf16* __restrict__ proj,
                                                      const float* __restrict__ sw) {
    const int e = threadIdx.x;              // 0..63, output element this lane owns
    const int bh = blockIdx.x;              // 0..127
    const int b = bh >> 4;
    const int h = bh & 15;

    // full-wave bpermute indices (bytes)
    const int idx_lo = (e & 31) << 2;
    const int idx_hi = ((e & 31) | 32) << 2;

    // state_weight [3*H, 64, 64]: Wc = sw[h], Wf = sw[16+h], Wr = sw[32+h]
    const float* Wc_p = sw + (size_t)h * 4096 + e;
    const float* Wf_p = Wc_p + (size_t)16 * 4096;
    const float* Wr_p = Wc_p + (size_t)32 * 4096;

    f32x2 Wc[32], Wf[32], Wr[32];           // pair (W[2dp][e], W[2dp+1][e])
    #pragma unroll
    for (int dp = 0; dp < 32; ++dp) {
        Wc[dp].x = Wc_p[(2 * dp) * 64]; Wc[dp].y = Wc_p[(2 * dp + 1) * 64];
        Wf[dp].x = Wf_p[(2 * dp) * 64]; Wf[dp].y = Wf_p[(2 * dp + 1) * 64];
        Wr[dp].x = Wr_p[(2 * dp) * 64]; Wr[dp].y = Wr_p[(2 * dp + 1) * 64];
    }

    bf16* xi_p = proj + (size_t)b * S_ * PROJ4 + h * 64 + e;   // cols [0:1024)
    const bf16* xf_p = xi_p + 1024;
    const bf16* xr_p = xi_p + 2048;

    float hreg = 0.0f;
    int hlo = 0, hhi = 0;                   // replicas of h=0

    // depth-2 register prefetch (~2 steps = >1000 cyc of cover, in-order wave
    // ensures loads precede the in-place h store of the same slot)
    float xi0 = __bfloat162float(xi_p[0]);
    float xf0 = __bfloat162float(xf_p[0]);
    float xr0 = __bfloat162float(xr_p[0]);
    float xi1 = __bfloat162float(xi_p[PROJ4]);
    float xf1 = __bfloat162float(xf_p[PROJ4]);
    float xr1 = __bfloat162float(xr_p[PROJ4]);

    #pragma unroll 1
    for (int t = 0; t < S_; ++t) {
        float xi2 = 0.f, xf2 = 0.f, xr2 = 0.f;
        if (t + 2 < S_) {
            size_t o = (size_t)(t + 2) * PROJ4;
            xi2 = __bfloat162float(xi_p[o]);
            xf2 = __bfloat162float(xf_p[o]);
            xr2 = __bfloat162float(xr_p[o]);
        }

        // r/f matvecs: 64 swizzle broadcasts shared by both gates
        f32x2 ar0 = {0.f, 0.f}, ar1 = {0.f, 0.f};
        f32x2 af0 = {0.f, 0.f}, af1 = {0.f, 0.f};
        RFLoop<0>::run(hlo, hhi, Wr, Wf, ar0, ar1, af0, af1);

        float sr = xr0 + ar0.x + ar0.y + ar1.x + ar1.y;
        float sf = xf0 + af0.x + af0.y + af1.x + af1.y;
        float r = __builtin_amdgcn_rcpf(1.f + __expf(-sr));
        float f = __builtin_amdgcn_rcpf(1.f + __expf(-sf));

        // candidate matvec on rh = r*h: make full-wave replicas, then swizzle
        float rh = r * hreg;
        int rlo = __builtin_amdgcn_ds_bpermute(idx_lo, __float_as_int(rh));
        int rhi = __builtin_amdgcn_ds_bpermute(idx_hi, __float_as_int(rh));
        f32x2 ac0 = {0.f, 0.f}, ac1 = {0.f, 0.f};
        CLoop<0>::run(rlo, rhi, Wc, ac0, ac1);

        float sc = xi0 + ac0.x + ac0.y + ac1.x + ac1.y;
        sc = fminf(fmaxf(sc, -15.f), 15.f);
        float ex = __expf(-2.f * sc);
        float c = (1.f - ex) * __builtin_amdgcn_rcpf(1.f + ex);   // tanh

        hreg = f * hreg + (1.f - f) * c;

        // refresh the half-replicas for next step (full-wave bpermute)
        hlo = __builtin_amdgcn_ds_bpermute(idx_lo, __float_as_int(hreg));
        hhi = __builtin_amdgcn_ds_bpermute(idx_hi, __float_as_int(hreg));

        // in-place h store over the consumed xi slot (fire-and-forget)
        xi_p[(size_t)t * PROJ4] = __float2bfloat16(hreg);

        xi0 = xi1; xf0 = xf1; xr0 = xr1;
        xi1 = xi2; xf1 = xf2; xr1 = xr2;
    }
}

// ---------------------------------------------------------------------------
// Gated RMSNorm in place over proj cols [0:1024).
// ---------------------------------------------------------------------------
__global__ __launch_bounds__(256) void gate_norm_kernel(bf16* __restrict__ proj,
                                                        const float* __restrict__ nw) {
    const int row = blockIdx.x;
    const int tid = threadIdx.x;
    __shared__ float red[4];

    bf16* hp = proj + (size_t)row * PROJ4;
    const bf16* gp = hp + 3 * DSTATE;

    float4 hv = load4(hp + tid * 4);
    float4 gv = load4(gp + tid * 4);

    float v0 = hv.x * (gv.x / (1.f + __expf(-gv.x)));
    float v1 = hv.y * (gv.y / (1.f + __expf(-gv.y)));
    float v2 = hv.z * (gv.z / (1.f + __expf(-gv.z)));
    float v3 = hv.w * (gv.w / (1.f + __expf(-gv.w)));

    float ss = v0 * v0 + v1 * v1 + v2 * v2 + v3 * v3;
    #pragma unroll
    for (int mask = 32; mask >= 1; mask >>= 1)
        ss += __shfl_xor(ss, mask, 64);

    const int wid = tid >> 6;
    if ((tid & 63) == 0) red[wid] = ss;
    __syncthreads();
    float tot = red[0] + red[1] + red[2] + red[3];
    float scale = rsqrtf(tot * (1.0f / (float)DSTATE) + 1e-6f);

    float4 nv = *(const float4*)(nw + tid * 4);
    float4 y;
    y.x = v0 * scale * nv.x;
    y.y = v1 * scale * nv.y;
    y.z = v2 * scale * nv.z;
    y.w = v3 * scale * nv.w;
    store4(hp + tid * 4, y);
}

// ---------------------------------------------------------------------------
extern "C" void kernel_launch(void* const* d_in, const int* in_sizes, int n_in,
                              void* d_out, int out_size, void* d_ws, size_t ws_size,
                              hipStream_t stream) {
    const float* x     = (const float*)d_in[0];   // [B,S,DIN]
    const float* w_in  = (const float*)d_in[1];   // [DIN, 4*DSTATE]
    const float* sw    = (const float*)d_in[2];   // [3H, DH, DH]
    const float* nw    = (const float*)d_in[3];   // [DSTATE]
    const float* w_out = (const float*)d_in[4];   // [DSTATE, DOUT]
    float* out = (float*)d_out;

    bf16* proj = (bf16*)d_ws;    // [B*S, 4096] bf16 = 134 MB (only ws use)

    // 1) input projection GEMM (MFMA bf16): [16384,1024] @ [1024,4096] -> bf16
    dim3 g1(PROJ4 / 128, (B_ * S_) / 128);
    gemm_mfma<float, bf16><<<g1, 256, 0, stream>>>(x, w_in, proj,
                                                   B_ * S_, PROJ4, DIN, DIN);

    // 2) sequential gated recurrence: 1 wave/chain, swizzle broadcasts
    recur_kernel<<<128, 64, 0, stream>>>(proj, sw);

    // 3) gate + rmsnorm in place over cols 0:1024
    gate_norm_kernel<<<B_ * S_, 256, 0, stream>>>(proj, nw);

    // 4) output projection GEMM (MFMA bf16): y(bf16, lda=4096) @ [1024,1024] -> f32
    dim3 g2(DSTATE / 128, (B_ * S_) / 128);
    gemm_mfma<bf16, float><<<g2, 256, 0, stream>>>(proj, w_out, out,
                                                   B_ * S_, DSTATE, DSTATE, PROJ4);
}